// Round 2
// baseline (532.954 us; speedup 1.0000x reference)
//
#include <hip/hip_runtime.h>
#include <hip/hip_bf16.h>
#include <float.h>

#define DIMS 64
#define KC 1024
#define M_TOTAL 65536
#define TAU_BF 1.0f   // bf16 dist-error std ~0.026 -> 25+ sigma margin

typedef __attribute__((ext_vector_type(8))) short bf16x8;   // 8 bf16 = 4 VGPRs
typedef __attribute__((ext_vector_type(4))) float f32x4;

// ---------------- ws layout (float elements) ----------------
#define SE_OFF   0                   // 1024 f32 codebook sq norms
#define PART_OFF 1024                // 1024 f32 loss partials
#define CNT_OFF  2048                // 1 int refine counter
#define WL_OFF   2304                // 65536 int worklist
#define IDX_OFF  (2304 + 65536)      // 65536 int argmin per row
#define PB_OFF   (2304 + 2*65536)    // 65536 bf16 packed codebook frags

__device__ inline short f2bf(float x) {
  union { __hip_bfloat16 h; short s; } u;
  u.h = __float2bfloat16(x);
  return u.s;
}

__global__ __launch_bounds__(256) void k_se(const float* __restrict__ cb,
                                            float* __restrict__ se,
                                            int* __restrict__ cnt) {
  if (blockIdx.x == 0 && threadIdx.x == 0) *cnt = 0;
  int k = blockIdx.x * 256 + threadIdx.x;
  const float4* p = (const float4*)(cb + (size_t)k * DIMS);
  float a0 = 0.f, a1 = 0.f, a2 = 0.f, a3 = 0.f;
#pragma unroll
  for (int i = 0; i < DIMS / 4; ++i) {
    float4 v = p[i];
    a0 = fmaf(v.x, v.x, a0);
    a1 = fmaf(v.y, v.y, a1);
    a2 = fmaf(v.z, v.z, a2);
    a3 = fmaf(v.w, v.w, a3);
  }
  se[k] = (a0 + a1) + (a2 + a3);
}

// pack codebook into bf16 MFMA B-fragment layout:
// pb[((tile*2 + kstep)*64 + lane)*8 + j] = cb_bf16[16*tile + (lane&15)][32*kstep + (lane>>4)*8 + j]
__global__ __launch_bounds__(256) void k_packB(const float* __restrict__ cb,
                                               unsigned short* __restrict__ pb) {
  const int tid = blockIdx.x * 256 + threadIdx.x;  // 8192 total
  const int l = tid & 63;
  const int s = (tid >> 6) & 1;
  const int tt = tid >> 7;
  const int code = tt * 16 + (l & 15);
  const int k = s * 32 + (l >> 4) * 8;
  const float* p = cb + (size_t)code * DIMS + k;
  float4 u = ((const float4*)p)[0];
  float4 v = ((const float4*)p)[1];
  bf16x8 b;
  b[0] = f2bf(u.x); b[1] = f2bf(u.y); b[2] = f2bf(u.z); b[3] = f2bf(u.w);
  b[4] = f2bf(v.x); b[5] = f2bf(v.y); b[6] = f2bf(v.z); b[7] = f2bf(v.w);
  *(bf16x8*)(pb + (size_t)tid * 8) = b;
}

// MFMA phase-1: per wave 16 rows x 1024 codes, rel-dist = se[c] - 2*dot.
// C/D layout (m89-verified): col = lane&15, row = (lane>>4)*4 + reg.
__global__ __launch_bounds__(256) void k_dist_mfma(const float* __restrict__ z,
                                                   const unsigned short* __restrict__ pb,
                                                   const float* __restrict__ se,
                                                   int* __restrict__ idxo,
                                                   int* __restrict__ wl,
                                                   int* __restrict__ cnt) {
  const int l = threadIdx.x & 63;
  const int w = threadIdx.x >> 6;
  const int r0 = blockIdx.x * 64 + w * 16;
  const int col = l & 15;
  const int g = l >> 4;

  // A fragments: z rows r0..r0+15, K=64 as 2 ksteps of 32; convert fp32->bf16 inline
  const float* zp = z + (size_t)(r0 + col) * DIMS + g * 8;
  bf16x8 a0, a1;
  {
    float4 u = ((const float4*)zp)[0];
    float4 v = ((const float4*)zp)[1];
    a0[0] = f2bf(u.x); a0[1] = f2bf(u.y); a0[2] = f2bf(u.z); a0[3] = f2bf(u.w);
    a0[4] = f2bf(v.x); a0[5] = f2bf(v.y); a0[6] = f2bf(v.z); a0[7] = f2bf(v.w);
    u = ((const float4*)(zp + 32))[0];
    v = ((const float4*)(zp + 32))[1];
    a1[0] = f2bf(u.x); a1[1] = f2bf(u.y); a1[2] = f2bf(u.z); a1[3] = f2bf(u.w);
    a1[4] = f2bf(v.x); a1[5] = f2bf(v.y); a1[6] = f2bf(v.z); a1[7] = f2bf(v.w);
  }

  const bf16x8* pbv = (const bf16x8*)pb;
  float m1[4] = {FLT_MAX, FLT_MAX, FLT_MAX, FLT_MAX};
  float m2[4] = {FLT_MAX, FLT_MAX, FLT_MAX, FLT_MAX};
  int bt[4] = {0, 0, 0, 0};

  for (int t = 0; t < 64; ++t) {
    bf16x8 b0 = pbv[t * 128 + l];
    bf16x8 b1 = pbv[t * 128 + 64 + l];
    f32x4 acc = {0.f, 0.f, 0.f, 0.f};
    acc = __builtin_amdgcn_mfma_f32_16x16x32_bf16(a0, b0, acc, 0, 0, 0);
    acc = __builtin_amdgcn_mfma_f32_16x16x32_bf16(a1, b1, acc, 0, 0, 0);
    float sec = se[t * 16 + col];
#pragma unroll
    for (int j = 0; j < 4; ++j) {
      float d = fmaf(-2.f, acc[j], sec);
      bool lt = d < m1[j];
      m2[j] = fminf(m2[j], lt ? m1[j] : d);
      m1[j] = fminf(m1[j], d);
      bt[j] = lt ? t : bt[j];
    }
  }

  // cross-lane reduce over the 16 cols of each row group; lowest-index tie-break
#pragma unroll
  for (int j = 0; j < 4; ++j) {
    float m1j = m1[j], m2j = m2[j];
    int ij = bt[j] * 16 + col;
    for (int msk = 1; msk <= 8; msk <<= 1) {
      float o1 = __shfl_xor(m1j, msk);
      float o2 = __shfl_xor(m2j, msk);
      int oi = __shfl_xor(ij, msk);
      bool take = (o1 < m1j) || (o1 == m1j && oi < ij);
      float hi = take ? m1j : o1;  // losing min1 becomes min2 candidate
      m2j = fminf(fminf(m2j, o2), hi);
      m1j = take ? o1 : m1j;
      ij = take ? oi : ij;
    }
    if (col == 0) {
      int row = r0 + g * 4 + j;
      idxo[row] = ij;
      if (m2j - m1j < TAU_BF) {
        int p = atomicAdd(cnt, 1);
        wl[p] = row;
      }
    }
  }
}

// exact fp64 diff-form re-resolution for flagged rows (worklist)
__global__ __launch_bounds__(256) void k_refine(const float* __restrict__ z,
                                                const float* __restrict__ cb,
                                                const int* __restrict__ wl,
                                                const int* __restrict__ cnt,
                                                int* __restrict__ idxo) {
  __shared__ float zz[64];
  __shared__ double sd[256];
  __shared__ int si[256];
  const int t = threadIdx.x;
  const int n = *cnt;
  for (int wi = blockIdx.x; wi < n; wi += 2048) {
    const int row = wl[wi];
    if (t < 16) ((float4*)zz)[t] = ((const float4*)(z + (size_t)row * DIMS))[t];
    __syncthreads();
    const int c0 = t * 4;
    double accd[4] = {0.0, 0.0, 0.0, 0.0};
    for (int ch = 0; ch < 4; ++ch) {
      float zr[16];
#pragma unroll
      for (int q = 0; q < 4; ++q) ((float4*)zr)[q] = ((float4*)zz)[ch * 4 + q];
#pragma unroll
      for (int cc = 0; cc < 4; ++cc) {
        const float* e = cb + (size_t)(c0 + cc) * DIMS + ch * 16;
#pragma unroll
        for (int q = 0; q < 16; ++q) {
          double df = (double)zr[q] - (double)e[q];
          accd[cc] = fma(df, df, accd[cc]);
        }
      }
    }
    double best = 1e300;
    int bi = 0;
#pragma unroll
    for (int cc = 0; cc < 4; ++cc) {
      if (accd[cc] < best) { best = accd[cc]; bi = c0 + cc; }
    }
    sd[t] = best;
    si[t] = bi;
    __syncthreads();
    for (int off = 128; off > 0; off >>= 1) {
      if (t < off) {
        double ob = sd[t + off];
        int oi = si[t + off];
        if (ob < sd[t] || (ob == sd[t] && oi < si[t])) { sd[t] = ob; si[t] = oi; }
      }
      __syncthreads();
    }
    if (t == 0) idxo[row] = si[0];
    __syncthreads();
  }
}

// gather + straight-through output (z + (e - z), ref rounding) + loss partials
__global__ __launch_bounds__(256) void k_out(const float* __restrict__ z,
                                             const float* __restrict__ cb,
                                             const int* __restrict__ idxi,
                                             float* __restrict__ out,
                                             float* __restrict__ partials) {
  const int tid = blockIdx.x * 256 + threadIdx.x;  // 262144: quarter-row each
  const int row = tid >> 2;
  const int q = tid & 3;
  const int code = idxi[row];
  const float4* zp = (const float4*)(z + (size_t)row * DIMS + q * 16);
  const float4* ep = (const float4*)(cb + (size_t)code * DIMS + q * 16);
  float4* op = (float4*)(out + (size_t)row * DIMS + q * 16);
  float sse = 0.f;
#pragma unroll
  for (int i = 0; i < 4; ++i) {
    float4 v = zp[i], e = ep[i];
    float dx = e.x - v.x, dy = e.y - v.y, dz = e.z - v.z, dw = e.w - v.w;
    sse = fmaf(dx, dx, sse);
    sse = fmaf(dy, dy, sse);
    sse = fmaf(dz, dz, sse);
    sse = fmaf(dw, dw, sse);
    float4 o;
    o.x = v.x + dx;
    o.y = v.y + dy;
    o.z = v.z + dz;
    o.w = v.w + dw;
    op[i] = o;
  }
  __shared__ float sh[256];
  sh[threadIdx.x] = sse;
  __syncthreads();
  for (int off = 128; off > 0; off >>= 1) {
    if (threadIdx.x < off) sh[threadIdx.x] += sh[threadIdx.x + off];
    __syncthreads();
  }
  if (threadIdx.x == 0) partials[blockIdx.x] = sh[0];
}

__global__ __launch_bounds__(256) void k_loss(const float* __restrict__ partials,
                                              float* __restrict__ out) {
  __shared__ float sh[256];
  const int t = threadIdx.x;
  sh[t] = partials[t] + partials[t + 256] + partials[t + 512] + partials[t + 768];
  __syncthreads();
  for (int off = 128; off > 0; off >>= 1) {
    if (t < off) sh[t] += sh[t + off];
    __syncthreads();
  }
  if (t == 0) {
    // (0.1*mse + mse) * 10 = 11 * SSE / (M*D)
    out[(size_t)M_TOTAL * DIMS] = sh[0] * (11.0f / (float)((size_t)M_TOTAL * DIMS));
  }
}

extern "C" void kernel_launch(void* const* d_in, const int* in_sizes, int n_in,
                              void* d_out, int out_size, void* d_ws, size_t ws_size,
                              hipStream_t stream) {
  const float* z = (const float*)d_in[0];
  const float* cb = (const float*)d_in[1];
  float* out = (float*)d_out;
  float* ws = (float*)d_ws;

  float* se = ws + SE_OFF;
  float* partials = ws + PART_OFF;
  int* cnt = (int*)(ws + CNT_OFF);
  int* wl = (int*)(ws + WL_OFF);
  int* idx = (int*)(ws + IDX_OFF);
  unsigned short* pb = (unsigned short*)(ws + PB_OFF);

  k_se<<<KC / 256, 256, 0, stream>>>(cb, se, cnt);
  k_packB<<<32, 256, 0, stream>>>(cb, pb);
  k_dist_mfma<<<M_TOTAL / 64, 256, 0, stream>>>(z, pb, se, idx, wl, cnt);
  k_refine<<<2048, 256, 0, stream>>>(z, cb, wl, cnt, idx);
  k_out<<<1024, 256, 0, stream>>>(z, cb, idx, out, partials);
  k_loss<<<1, 256, 0, stream>>>(partials, out);
}

// Round 3
// 71.632 us; speedup vs baseline: 7.4402x; 7.4402x over previous
//
#include <hip/hip_runtime.h>
#include <hip/hip_bf16.h>
#include <float.h>

#define DIMS 64
#define KC 1024
#define M_TOTAL 65536
#define TAU 4e-3f   // split-bf16 dist err ~2e-5 std -> ~200 sigma margin

typedef __attribute__((ext_vector_type(8))) short bf16x8;   // 8 bf16 = 4 VGPRs
typedef __attribute__((ext_vector_type(4))) float f32x4;

// ---------------- ws layout (float elements) ----------------
#define SE_OFF   0                    // 1024 f32 codebook sq norms
#define PART_OFF 1024                 // 1024 f32 loss partials
#define CNT_OFF  2048                 // 1 int refine counter
#define WL_OFF   2304                 // 65536 int worklist
#define IDX_OFF  (2304 + 65536)       // 65536 int argmin per row
#define PBH_OFF  (2304 + 2*65536)     // 65536 bf16 packed codebook hi frags (32768 f32)
#define PBL_OFF  (PBH_OFF + 32768)    // 65536 bf16 packed codebook lo frags

__device__ inline short f2bf(float x) {
  union { __hip_bfloat16 h; short s; } u;
  u.h = __float2bfloat16(x);
  return u.s;
}
__device__ inline float bf2f(short x) {
  union { short s; __hip_bfloat16 h; } u;
  u.s = x;
  return __bfloat162float(u.h);
}

__global__ __launch_bounds__(256) void k_se(const float* __restrict__ cb,
                                            float* __restrict__ se,
                                            int* __restrict__ cnt) {
  if (blockIdx.x == 0 && threadIdx.x == 0) *cnt = 0;
  int k = blockIdx.x * 256 + threadIdx.x;
  const float4* p = (const float4*)(cb + (size_t)k * DIMS);
  float a0 = 0.f, a1 = 0.f, a2 = 0.f, a3 = 0.f;
#pragma unroll
  for (int i = 0; i < DIMS / 4; ++i) {
    float4 v = p[i];
    a0 = fmaf(v.x, v.x, a0);
    a1 = fmaf(v.y, v.y, a1);
    a2 = fmaf(v.z, v.z, a2);
    a3 = fmaf(v.w, v.w, a3);
  }
  se[k] = (a0 + a1) + (a2 + a3);
}

// pack codebook into bf16 MFMA B-fragment layout, hi + lo residue:
// frag[((tile*2 + kstep)*64 + lane)*8 + j] = E[16*tile + (lane&15)][32*kstep + (lane>>4)*8 + j]
__global__ __launch_bounds__(256) void k_packB(const float* __restrict__ cb,
                                               unsigned short* __restrict__ pbh,
                                               unsigned short* __restrict__ pbl) {
  const int tid = blockIdx.x * 256 + threadIdx.x;  // 8192 total
  const int l = tid & 63;
  const int s = (tid >> 6) & 1;
  const int tt = tid >> 7;
  const int code = tt * 16 + (l & 15);
  const int k = s * 32 + (l >> 4) * 8;
  const float* p = cb + (size_t)code * DIMS + k;
  float v[8];
  ((float4*)v)[0] = ((const float4*)p)[0];
  ((float4*)v)[1] = ((const float4*)p)[1];
  bf16x8 h, lo;
#pragma unroll
  for (int j = 0; j < 8; ++j) {
    short hj = f2bf(v[j]);
    h[j] = hj;
    lo[j] = f2bf(v[j] - bf2f(hj));
  }
  *(bf16x8*)(pbh + (size_t)tid * 8) = h;
  *(bf16x8*)(pbl + (size_t)tid * 8) = lo;
}

// MFMA phase-1 (split bf16 ~ fp32 accuracy): rel-dist = se[c] - 2*(zh.eh + zh.el + zl.eh)
// C/D layout (m89-verified): col = lane&15, row = (lane>>4)*4 + reg.
__global__ __launch_bounds__(256) void k_dist_mfma(const float* __restrict__ z,
                                                   const unsigned short* __restrict__ pbh,
                                                   const unsigned short* __restrict__ pbl,
                                                   const float* __restrict__ se,
                                                   int* __restrict__ idxo,
                                                   int* __restrict__ wl,
                                                   int* __restrict__ cnt) {
  const int l = threadIdx.x & 63;
  const int w = threadIdx.x >> 6;
  const int r0 = blockIdx.x * 64 + w * 16;
  const int col = l & 15;
  const int g = l >> 4;

  // A fragments (hi + lo residue): z rows r0..r0+15, K=64 as 2 ksteps of 32
  const float* zp = z + (size_t)(r0 + col) * DIMS + g * 8;
  bf16x8 a0h, a1h, a0l, a1l;
  {
    float v[8];
    ((float4*)v)[0] = ((const float4*)zp)[0];
    ((float4*)v)[1] = ((const float4*)zp)[1];
#pragma unroll
    for (int j = 0; j < 8; ++j) {
      short hj = f2bf(v[j]);
      a0h[j] = hj;
      a0l[j] = f2bf(v[j] - bf2f(hj));
    }
    ((float4*)v)[0] = ((const float4*)(zp + 32))[0];
    ((float4*)v)[1] = ((const float4*)(zp + 32))[1];
#pragma unroll
    for (int j = 0; j < 8; ++j) {
      short hj = f2bf(v[j]);
      a1h[j] = hj;
      a1l[j] = f2bf(v[j] - bf2f(hj));
    }
  }

  const bf16x8* pbhv = (const bf16x8*)pbh;
  const bf16x8* pblv = (const bf16x8*)pbl;
  float m1[4] = {FLT_MAX, FLT_MAX, FLT_MAX, FLT_MAX};
  float m2[4] = {FLT_MAX, FLT_MAX, FLT_MAX, FLT_MAX};
  int bt[4] = {0, 0, 0, 0};

  for (int t = 0; t < 64; ++t) {
    bf16x8 b0h = pbhv[t * 128 + l];
    bf16x8 b1h = pbhv[t * 128 + 64 + l];
    bf16x8 b0l = pblv[t * 128 + l];
    bf16x8 b1l = pblv[t * 128 + 64 + l];
    // two independent accumulator chains (kstep0 / kstep1) for MFMA ILP
    f32x4 accA = {0.f, 0.f, 0.f, 0.f};
    f32x4 accB = {0.f, 0.f, 0.f, 0.f};
    accA = __builtin_amdgcn_mfma_f32_16x16x32_bf16(a0h, b0h, accA, 0, 0, 0);
    accB = __builtin_amdgcn_mfma_f32_16x16x32_bf16(a1h, b1h, accB, 0, 0, 0);
    accA = __builtin_amdgcn_mfma_f32_16x16x32_bf16(a0h, b0l, accA, 0, 0, 0);
    accB = __builtin_amdgcn_mfma_f32_16x16x32_bf16(a1h, b1l, accB, 0, 0, 0);
    accA = __builtin_amdgcn_mfma_f32_16x16x32_bf16(a0l, b0h, accA, 0, 0, 0);
    accB = __builtin_amdgcn_mfma_f32_16x16x32_bf16(a1l, b1h, accB, 0, 0, 0);
    float sec = se[t * 16 + col];
#pragma unroll
    for (int j = 0; j < 4; ++j) {
      float d = fmaf(-2.f, accA[j] + accB[j], sec);
      bool lt = d < m1[j];
      m2[j] = fminf(m2[j], lt ? m1[j] : d);
      m1[j] = fminf(m1[j], d);
      bt[j] = lt ? t : bt[j];
    }
  }

  // cross-lane reduce over the 16 cols of each row group; lowest-index tie-break
#pragma unroll
  for (int j = 0; j < 4; ++j) {
    float m1j = m1[j], m2j = m2[j];
    int ij = bt[j] * 16 + col;
    for (int msk = 1; msk <= 8; msk <<= 1) {
      float o1 = __shfl_xor(m1j, msk);
      float o2 = __shfl_xor(m2j, msk);
      int oi = __shfl_xor(ij, msk);
      bool take = (o1 < m1j) || (o1 == m1j && oi < ij);
      float hi = take ? m1j : o1;  // losing min1 becomes min2 candidate
      m2j = fminf(fminf(m2j, o2), hi);
      m1j = take ? o1 : m1j;
      ij = take ? oi : ij;
    }
    if (col == 0) {
      int row = r0 + g * 4 + j;
      idxo[row] = ij;
      if (m2j - m1j < TAU) {
        int p = atomicAdd(cnt, 1);
        wl[p] = row;
      }
    }
  }
}

// exact fp64 diff-form re-resolution for flagged rows (worklist, ~1% of rows)
__global__ __launch_bounds__(256) void k_refine(const float* __restrict__ z,
                                                const float* __restrict__ cb,
                                                const int* __restrict__ wl,
                                                const int* __restrict__ cnt,
                                                int* __restrict__ idxo) {
  __shared__ float zz[64];
  __shared__ double sd[256];
  __shared__ int si[256];
  const int t = threadIdx.x;
  const int n = *cnt;
  for (int wi = blockIdx.x; wi < n; wi += 2048) {
    const int row = wl[wi];
    if (t < 16) ((float4*)zz)[t] = ((const float4*)(z + (size_t)row * DIMS))[t];
    __syncthreads();
    const int c0 = t * 4;
    double accd[4] = {0.0, 0.0, 0.0, 0.0};
    for (int ch = 0; ch < 4; ++ch) {
      float zr[16];
#pragma unroll
      for (int q = 0; q < 4; ++q) ((float4*)zr)[q] = ((float4*)zz)[ch * 4 + q];
#pragma unroll
      for (int cc = 0; cc < 4; ++cc) {
        const float* e = cb + (size_t)(c0 + cc) * DIMS + ch * 16;
#pragma unroll
        for (int q = 0; q < 16; ++q) {
          double df = (double)zr[q] - (double)e[q];
          accd[cc] = fma(df, df, accd[cc]);
        }
      }
    }
    double best = 1e300;
    int bi = 0;
#pragma unroll
    for (int cc = 0; cc < 4; ++cc) {
      if (accd[cc] < best) { best = accd[cc]; bi = c0 + cc; }
    }
    sd[t] = best;
    si[t] = bi;
    __syncthreads();
    for (int off = 128; off > 0; off >>= 1) {
      if (t < off) {
        double ob = sd[t + off];
        int oi = si[t + off];
        if (ob < sd[t] || (ob == sd[t] && oi < si[t])) { sd[t] = ob; si[t] = oi; }
      }
      __syncthreads();
    }
    if (t == 0) idxo[row] = si[0];
    __syncthreads();
  }
}

// gather + straight-through output (z + (e - z), ref rounding) + loss partials
__global__ __launch_bounds__(256) void k_out(const float* __restrict__ z,
                                             const float* __restrict__ cb,
                                             const int* __restrict__ idxi,
                                             float* __restrict__ out,
                                             float* __restrict__ partials) {
  const int tid = blockIdx.x * 256 + threadIdx.x;  // 262144: quarter-row each
  const int row = tid >> 2;
  const int q = tid & 3;
  const int code = idxi[row];
  const float4* zp = (const float4*)(z + (size_t)row * DIMS + q * 16);
  const float4* ep = (const float4*)(cb + (size_t)code * DIMS + q * 16);
  float4* op = (float4*)(out + (size_t)row * DIMS + q * 16);
  float sse = 0.f;
#pragma unroll
  for (int i = 0; i < 4; ++i) {
    float4 v = zp[i], e = ep[i];
    float dx = e.x - v.x, dy = e.y - v.y, dz = e.z - v.z, dw = e.w - v.w;
    sse = fmaf(dx, dx, sse);
    sse = fmaf(dy, dy, sse);
    sse = fmaf(dz, dz, sse);
    sse = fmaf(dw, dw, sse);
    float4 o;
    o.x = v.x + dx;
    o.y = v.y + dy;
    o.z = v.z + dz;
    o.w = v.w + dw;
    op[i] = o;
  }
  __shared__ float sh[256];
  sh[threadIdx.x] = sse;
  __syncthreads();
  for (int off = 128; off > 0; off >>= 1) {
    if (threadIdx.x < off) sh[threadIdx.x] += sh[threadIdx.x + off];
    __syncthreads();
  }
  if (threadIdx.x == 0) partials[blockIdx.x] = sh[0];
}

__global__ __launch_bounds__(256) void k_loss(const float* __restrict__ partials,
                                              float* __restrict__ out) {
  __shared__ float sh[256];
  const int t = threadIdx.x;
  sh[t] = partials[t] + partials[t + 256] + partials[t + 512] + partials[t + 768];
  __syncthreads();
  for (int off = 128; off > 0; off >>= 1) {
    if (t < off) sh[t] += sh[t + off];
    __syncthreads();
  }
  if (t == 0) {
    // (0.1*mse + mse) * 10 = 11 * SSE / (M*D)
    out[(size_t)M_TOTAL * DIMS] = sh[0] * (11.0f / (float)((size_t)M_TOTAL * DIMS));
  }
}

extern "C" void kernel_launch(void* const* d_in, const int* in_sizes, int n_in,
                              void* d_out, int out_size, void* d_ws, size_t ws_size,
                              hipStream_t stream) {
  const float* z = (const float*)d_in[0];
  const float* cb = (const float*)d_in[1];
  float* out = (float*)d_out;
  float* ws = (float*)d_ws;

  float* se = ws + SE_OFF;
  float* partials = ws + PART_OFF;
  int* cnt = (int*)(ws + CNT_OFF);
  int* wl = (int*)(ws + WL_OFF);
  int* idx = (int*)(ws + IDX_OFF);
  unsigned short* pbh = (unsigned short*)(ws + PBH_OFF);
  unsigned short* pbl = (unsigned short*)(ws + PBL_OFF);

  k_se<<<KC / 256, 256, 0, stream>>>(cb, se, cnt);
  k_packB<<<32, 256, 0, stream>>>(cb, pbh, pbl);
  k_dist_mfma<<<M_TOTAL / 64, 256, 0, stream>>>(z, pbh, pbl, se, idx, wl, cnt);
  k_refine<<<2048, 256, 0, stream>>>(z, cb, wl, cnt, idx);
  k_out<<<1024, 256, 0, stream>>>(z, cb, idx, out, partials);
  k_loss<<<1, 256, 0, stream>>>(partials, out);
}

// Round 4
// 69.863 us; speedup vs baseline: 7.6285x; 1.0253x over previous
//
#include <hip/hip_runtime.h>
#include <hip/hip_bf16.h>
#include <float.h>

#define DIMS 64
#define KC 1024
#define M_TOTAL 65536
#define TAU 4e-3f   // split-bf16 dist err ~2e-5 std -> ~200 sigma margin

typedef __attribute__((ext_vector_type(8))) short bf16x8;   // 8 bf16 = 4 VGPRs
typedef __attribute__((ext_vector_type(4))) float f32x4;

// ---------------- ws layout (float elements) ----------------
#define SE_OFF   0                       // 1024 f32 codebook sq norms
#define PART_OFF 1024                    // 2048 f32 loss partials
#define PBH_OFF  4096                    // 65536 bf16 hi frags (32768 f32)
#define PBL_OFF  (PBH_OFF + 32768)       // 65536 bf16 lo frags (prefetch overreads into M1 - safe)
#define M1_OFF   (PBL_OFF + 32768)       // 2*65536 f32 per-split min1
#define M2_OFF   (M1_OFF + 2*65536)      // 2*65536 f32 per-split min2
#define IDXS_OFF (M2_OFF + 2*65536)      // 2*65536 int per-split argmin

__device__ inline short f2bf(float x) {
  union { __hip_bfloat16 h; short s; } u;
  u.h = __float2bfloat16(x);
  return u.s;
}
__device__ inline float bf2f(short x) {
  union { short s; __hip_bfloat16 h; } u;
  u.s = x;
  return __bfloat162float(u.h);
}

// fused: pack codebook into bf16 MFMA B-fragment layout (hi + lo residue) + sq norms
// frag[((tile*2 + kstep)*64 + lane)*8 + j] = E[16*tile + (lane&15)][32*kstep + (lane>>4)*8 + j]
__global__ __launch_bounds__(256) void k_prep(const float* __restrict__ cb,
                                              float* __restrict__ se,
                                              unsigned short* __restrict__ pbh,
                                              unsigned short* __restrict__ pbl) {
  const int tid = blockIdx.x * 256 + threadIdx.x;  // 8192 total
  const int l = tid & 63;
  const int s = (tid >> 6) & 1;
  const int tt = tid >> 7;
  const int code = tt * 16 + (l & 15);
  const int k = s * 32 + (l >> 4) * 8;
  const float* p = cb + (size_t)code * DIMS + k;
  float v[8];
  ((float4*)v)[0] = ((const float4*)p)[0];
  ((float4*)v)[1] = ((const float4*)p)[1];
  bf16x8 h, lo;
#pragma unroll
  for (int j = 0; j < 8; ++j) {
    short hj = f2bf(v[j]);
    h[j] = hj;
    lo[j] = f2bf(v[j] - bf2f(hj));
  }
  *(bf16x8*)(pbh + (size_t)tid * 8) = h;
  *(bf16x8*)(pbl + (size_t)tid * 8) = lo;

  if (tid < KC) {
    const float4* q = (const float4*)(cb + (size_t)tid * DIMS);
    float a0 = 0.f, a1 = 0.f, a2 = 0.f, a3 = 0.f;
#pragma unroll
    for (int i = 0; i < DIMS / 4; ++i) {
      float4 u = q[i];
      a0 = fmaf(u.x, u.x, a0);
      a1 = fmaf(u.y, u.y, a1);
      a2 = fmaf(u.z, u.z, a2);
      a3 = fmaf(u.w, u.w, a3);
    }
    se[tid] = (a0 + a1) + (a2 + a3);
  }
}

// MFMA phase-1 (split bf16): wave = 32 rows x 512 codes. rel-dist = se[c] - 2*dot.
// C/D layout (m89-verified): col = lane&15, row = (lane>>4)*4 + reg.
__global__ __launch_bounds__(256, 4) void k_dist(const float* __restrict__ z,
                                                 const unsigned short* __restrict__ pbh,
                                                 const unsigned short* __restrict__ pbl,
                                                 const float* __restrict__ se,
                                                 float* __restrict__ m1o,
                                                 float* __restrict__ m2o,
                                                 int* __restrict__ idxo) {
  const int l = threadIdx.x & 63;
  const int w = threadIdx.x >> 6;
  const int split = blockIdx.x & 1;
  const int rb = blockIdx.x >> 1;
  const int r0 = rb * 128 + w * 32;   // wave owns rows r0..r0+31
  const int col = l & 15;
  const int g = l >> 4;

  // A fragments (hi + lo residue), 2 row-sets x 2 ksteps
  bf16x8 ah[2][2], al[2][2];
#pragma unroll
  for (int rs = 0; rs < 2; ++rs) {
    const float* zp = z + (size_t)(r0 + rs * 16 + col) * DIMS + g * 8;
#pragma unroll
    for (int ks = 0; ks < 2; ++ks) {
      float v[8];
      ((float4*)v)[0] = ((const float4*)(zp + ks * 32))[0];
      ((float4*)v)[1] = ((const float4*)(zp + ks * 32))[1];
      bf16x8 h, lo;
#pragma unroll
      for (int j = 0; j < 8; ++j) {
        short hj = f2bf(v[j]);
        h[j] = hj;
        lo[j] = f2bf(v[j] - bf2f(hj));
      }
      ah[rs][ks] = h;
      al[rs][ks] = lo;
    }
  }

  const bf16x8* ph = (const bf16x8*)pbh + (size_t)(split * 32) * 128 + l;
  const bf16x8* pq = (const bf16x8*)pbl + (size_t)(split * 32) * 128 + l;
  const float* sep = se + split * 512 + col;

  float m1[2][4], m2[2][4];
  int bt[2][4];
#pragma unroll
  for (int rs = 0; rs < 2; ++rs)
#pragma unroll
    for (int j = 0; j < 4; ++j) {
      m1[rs][j] = FLT_MAX;
      m2[rs][j] = FLT_MAX;
      bt[rs][j] = 0;
    }

  // prefetch tile 0
  bf16x8 nh0 = ph[0], nh1 = ph[64], nl0 = pq[0], nl1 = pq[64];
  for (int t = 0; t < 32; ++t) {
    bf16x8 bh0 = nh0, bh1 = nh1, bl0 = nl0, bl1 = nl1;
    ph += 128;
    pq += 128;
    nh0 = ph[0];   // t=31 overreads into the next ws region: allocated, unused
    nh1 = ph[64];
    nl0 = pq[0];
    nl1 = pq[64];
    const float sec = sep[t * 16];
    f32x4 acc0 = {0.f, 0.f, 0.f, 0.f};
    f32x4 acc1 = {0.f, 0.f, 0.f, 0.f};
    acc0 = __builtin_amdgcn_mfma_f32_16x16x32_bf16(ah[0][0], bh0, acc0, 0, 0, 0);
    acc1 = __builtin_amdgcn_mfma_f32_16x16x32_bf16(ah[1][0], bh0, acc1, 0, 0, 0);
    acc0 = __builtin_amdgcn_mfma_f32_16x16x32_bf16(ah[0][1], bh1, acc0, 0, 0, 0);
    acc1 = __builtin_amdgcn_mfma_f32_16x16x32_bf16(ah[1][1], bh1, acc1, 0, 0, 0);
    acc0 = __builtin_amdgcn_mfma_f32_16x16x32_bf16(ah[0][0], bl0, acc0, 0, 0, 0);
    acc1 = __builtin_amdgcn_mfma_f32_16x16x32_bf16(ah[1][0], bl0, acc1, 0, 0, 0);
    acc0 = __builtin_amdgcn_mfma_f32_16x16x32_bf16(ah[0][1], bl1, acc0, 0, 0, 0);
    acc1 = __builtin_amdgcn_mfma_f32_16x16x32_bf16(ah[1][1], bl1, acc1, 0, 0, 0);
    acc0 = __builtin_amdgcn_mfma_f32_16x16x32_bf16(al[0][0], bh0, acc0, 0, 0, 0);
    acc1 = __builtin_amdgcn_mfma_f32_16x16x32_bf16(al[1][0], bh0, acc1, 0, 0, 0);
    acc0 = __builtin_amdgcn_mfma_f32_16x16x32_bf16(al[0][1], bh1, acc0, 0, 0, 0);
    acc1 = __builtin_amdgcn_mfma_f32_16x16x32_bf16(al[1][1], bh1, acc1, 0, 0, 0);
#pragma unroll
    for (int rs = 0; rs < 2; ++rs) {
      const f32x4 acc = rs ? acc1 : acc0;
#pragma unroll
      for (int j = 0; j < 4; ++j) {
        float d = fmaf(-2.f, acc[j], sec);
        m2[rs][j] = __builtin_amdgcn_fmed3f(d, m1[rs][j], m2[rs][j]);  // new 2nd-min
        bool lt = d < m1[rs][j];
        bt[rs][j] = lt ? t : bt[rs][j];
        m1[rs][j] = fminf(m1[rs][j], d);
      }
    }
  }

  // cross-lane reduce over the 16 cols of each row group; lowest-index tie-break
  const int c0 = split * 512;
#pragma unroll
  for (int rs = 0; rs < 2; ++rs)
#pragma unroll
    for (int j = 0; j < 4; ++j) {
      float m1j = m1[rs][j], m2j = m2[rs][j];
      int ij = c0 + bt[rs][j] * 16 + col;
      for (int msk = 1; msk <= 8; msk <<= 1) {
        float o1 = __shfl_xor(m1j, msk);
        float o2 = __shfl_xor(m2j, msk);
        int oi = __shfl_xor(ij, msk);
        bool take = (o1 < m1j) || (o1 == m1j && oi < ij);
        float hi = take ? m1j : o1;  // losing min1 becomes min2 candidate
        m2j = fminf(fminf(m2j, o2), hi);
        m1j = take ? o1 : m1j;
        ij = take ? oi : ij;
      }
      if (col == 0) {
        const int o = split * M_TOTAL + r0 + rs * 16 + g * 4 + j;
        m1o[o] = m1j;
        m2o[o] = m2j;
        idxo[o] = ij;
      }
    }
}

// fused: split-merge + flag + block-local exact fp64 refine + gather/output + loss partials
__global__ __launch_bounds__(256) void k_fin(const float* __restrict__ z,
                                             const float* __restrict__ cb,
                                             const float* __restrict__ m1s,
                                             const float* __restrict__ m2s,
                                             const int* __restrict__ idxs,
                                             float* __restrict__ out,
                                             float* __restrict__ partials) {
  const int t = threadIdx.x;
  const int rb = blockIdx.x;  // 2048 blocks x 32 rows
  __shared__ int s_idx[32];
  __shared__ int s_rows[32];
  __shared__ int s_n;
  __shared__ float zz[64];
  __shared__ double sd[256];
  __shared__ int si[256];
  __shared__ float s_sse[256];

  if (t == 0) s_n = 0;
  __syncthreads();

  if (t < 32) {
    const int row = rb * 32 + t;
    const float a1 = m1s[row], a2 = m2s[row];
    const float b1 = m1s[M_TOTAL + row], b2 = m2s[M_TOTAL + row];
    const int ia = idxs[row], ib = idxs[M_TOTAL + row];
    const float m1 = fminf(a1, b1);
    const float m2 = fminf(fmaxf(a1, b1), fminf(a2, b2));
    s_idx[t] = (b1 < a1) ? ib : ia;  // tie -> split 0 (lower code index)
    if (m2 - m1 < TAU) {
      int p = atomicAdd(&s_n, 1);
      s_rows[p] = t;
    }
  }
  __syncthreads();

  // block-cooperative exact fp64 recompute for flagged rows (rare)
  const int nf = s_n;
  for (int f = 0; f < nf; ++f) {
    const int lrow = s_rows[f];
    const int frow = rb * 32 + lrow;
    if (t < 16) ((float4*)zz)[t] = ((const float4*)(z + (size_t)frow * DIMS))[t];
    __syncthreads();
    const int c0 = t * 4;
    double accd[4] = {0.0, 0.0, 0.0, 0.0};
    for (int ch = 0; ch < 4; ++ch) {
      float zr[16];
#pragma unroll
      for (int q = 0; q < 4; ++q) ((float4*)zr)[q] = ((float4*)zz)[ch * 4 + q];
#pragma unroll
      for (int cc = 0; cc < 4; ++cc) {
        const float* e = cb + (size_t)(c0 + cc) * DIMS + ch * 16;
#pragma unroll
        for (int q = 0; q < 16; ++q) {
          double df = (double)zr[q] - (double)e[q];
          accd[cc] = fma(df, df, accd[cc]);
        }
      }
    }
    double best = 1e300;
    int bi = 0;
#pragma unroll
    for (int cc = 0; cc < 4; ++cc)
      if (accd[cc] < best) { best = accd[cc]; bi = c0 + cc; }
    sd[t] = best;
    si[t] = bi;
    __syncthreads();
    for (int off = 128; off > 0; off >>= 1) {
      if (t < off) {
        double ob = sd[t + off];
        int oi = si[t + off];
        if (ob < sd[t] || (ob == sd[t] && oi < si[t])) { sd[t] = ob; si[t] = oi; }
      }
      __syncthreads();
    }
    if (t == 0) s_idx[lrow] = si[0];
    __syncthreads();
  }

  // gather + straight-through output (z + (e - z), ref rounding) + loss partial
  const int lr = t >> 3;           // local row 0..31
  const int q = t & 7;             // 8 floats per thread
  const int row = rb * 32 + lr;
  const int code = s_idx[lr];
  const float4* zp = (const float4*)(z + (size_t)row * DIMS + q * 8);
  const float4* ep = (const float4*)(cb + (size_t)code * DIMS + q * 8);
  float4* op = (float4*)(out + (size_t)row * DIMS + q * 8);
  float sse = 0.f;
#pragma unroll
  for (int i = 0; i < 2; ++i) {
    float4 v = zp[i], e = ep[i];
    float dx = e.x - v.x, dy = e.y - v.y, dz = e.z - v.z, dw = e.w - v.w;
    sse = fmaf(dx, dx, sse);
    sse = fmaf(dy, dy, sse);
    sse = fmaf(dz, dz, sse);
    sse = fmaf(dw, dw, sse);
    float4 o;
    o.x = v.x + dx;
    o.y = v.y + dy;
    o.z = v.z + dz;
    o.w = v.w + dw;
    op[i] = o;
  }
  s_sse[t] = sse;
  __syncthreads();
  for (int off = 128; off > 0; off >>= 1) {
    if (t < off) s_sse[t] += s_sse[t + off];
    __syncthreads();
  }
  if (t == 0) partials[rb] = s_sse[0];
}

__global__ __launch_bounds__(256) void k_loss(const float* __restrict__ partials,
                                              float* __restrict__ out) {
  __shared__ float sh[256];
  const int t = threadIdx.x;
  float s = 0.f;
#pragma unroll
  for (int i = 0; i < 8; ++i) s += partials[t + i * 256];
  sh[t] = s;
  __syncthreads();
  for (int off = 128; off > 0; off >>= 1) {
    if (t < off) sh[t] += sh[t + off];
    __syncthreads();
  }
  if (t == 0) {
    // (0.1*mse + mse) * 10 = 11 * SSE / (M*D)
    out[(size_t)M_TOTAL * DIMS] = sh[0] * (11.0f / (float)((size_t)M_TOTAL * DIMS));
  }
}

extern "C" void kernel_launch(void* const* d_in, const int* in_sizes, int n_in,
                              void* d_out, int out_size, void* d_ws, size_t ws_size,
                              hipStream_t stream) {
  const float* z = (const float*)d_in[0];
  const float* cb = (const float*)d_in[1];
  float* out = (float*)d_out;
  float* ws = (float*)d_ws;

  float* se = ws + SE_OFF;
  float* partials = ws + PART_OFF;
  unsigned short* pbh = (unsigned short*)(ws + PBH_OFF);
  unsigned short* pbl = (unsigned short*)(ws + PBL_OFF);
  float* m1s = ws + M1_OFF;
  float* m2s = ws + M2_OFF;
  int* idxs = (int*)(ws + IDXS_OFF);

  k_prep<<<32, 256, 0, stream>>>(cb, se, pbh, pbl);
  k_dist<<<(M_TOTAL / 128) * 2, 256, 0, stream>>>(z, pbh, pbl, se, m1s, m2s, idxs);
  k_fin<<<M_TOTAL / 32, 256, 0, stream>>>(z, cb, m1s, m2s, idxs, out, partials);
  k_loss<<<1, 256, 0, stream>>>(partials, out);
}